// Round 6
// baseline (820.359 us; speedup 1.0000x reference)
//
#include <hip/hip_runtime.h>
#include <stdint.h>
#include <stddef.h>

// Problem constants
#define B_ 4
#define L_ 8192
#define D_ 512
#define M_ (B_*L_)      // 32768 rows
#define K_ 512
#define CHUNK 64
#define NCHUNK (M_/CHUNK)    // 512 chunks total
#define NC_SEQ (L_/CHUNK)    // 128 chunks per sequence

typedef _Float16 f16;
typedef f16 f16x2 __attribute__((ext_vector_type(2)));
typedef f16 f16x4 __attribute__((ext_vector_type(4)));
typedef f16 f16x8 __attribute__((ext_vector_type(8)));
typedef __fp16 h16x2 __attribute__((ext_vector_type(2)));   // cvt_pkrtz result type
typedef float f32x4 __attribute__((ext_vector_type(4)));

__device__ __forceinline__ uint32_t pack2(float a, float b) {
  h16x2 p = __builtin_amdgcn_cvt_pkrtz(a, b);
  return __builtin_bit_cast(uint32_t, p);
}

// ---------------- async global->LDS (16B/lane) ----------------
__device__ __forceinline__ void async16(const void* g, void* l) {
  __builtin_amdgcn_global_load_lds(
      (const __attribute__((address_space(1))) uint32_t*)g,
      (__attribute__((address_space(3))) uint32_t*)l,
      16, 0, 0);
}

// ---------------- prep: cvt x -> f16, pack W -> f16, clear flags ---------
// blocks [0, 16384)        : x fp32 -> f16
// blocks [16384, 16896)    : Wg++Wc fp32 -> f16 packed [1024][512]
// block  16896             : clear flags + vbid counter
__global__ __launch_bounds__(256) void prep(
    const float* __restrict__ x, const float* __restrict__ Wg,
    const float* __restrict__ Wc, f16* __restrict__ xh,
    f16* __restrict__ wp, uint32_t* __restrict__ flags,
    uint32_t* __restrict__ counter) {
  const int blk = blockIdx.x;
  const int tid = threadIdx.x;
  if (blk < 16384) {
    int idx = (blk * 256 + tid) * 4;
    float4 v = *(const float4*)(x + idx);
    f16x4 o = {(f16)v.x, (f16)v.y, (f16)v.z, (f16)v.w};
    *(f16x4*)(xh + idx) = o;
  } else if (blk < 16896) {
    int idx = ((blk - 16384) * 256 + tid) * 4;   // 0..524287
    const float* src = (idx < 262144) ? (Wg + idx) : (Wc + (idx - 262144));
    float4 v = *(const float4*)src;
    f16x4 o = {(f16)v.x, (f16)v.y, (f16)v.z, (f16)v.w};
    *(f16x4*)(wp + idx) = o;
  } else {
    flags[tid] = 0u;
    flags[tid + 256] = 0u;
    if (tid == 0) *counter = 0u;
  }
}

// ---------------- fused dual-B GEMM, packed f16x2 pre-activation out -----
// yg = Xh·Wg^T + bg ; yc = Xh·Wc^T + bc
// AC[m*512 + col] = pack_f16x2(yg, yc)   (activations applied in scan)
__global__ __launch_bounds__(256, 4) void gemm_act(
    const f16* __restrict__ Xh, const f16* __restrict__ Wp,
    const float* __restrict__ bg, const float* __restrict__ bc,
    uint32_t* __restrict__ AC) {
  __shared__ __align__(16) f16 sA[128 * 32];
  __shared__ __align__(16) f16 sBg[128 * 32];
  __shared__ __align__(16) f16 sBc[128 * 32];

  const int tid = threadIdx.x;
  // XCD swizzle: same bm-tile's 4 col-blocks run consecutively on one XCD
  const int id = blockIdx.x;           // 0..1023
  const int xcd = id & 7;
  const int slot = id >> 3;            // 0..127
  const int g_ = xcd * 128 + slot;
  const int bm = g_ >> 2;              // 0..255
  const int bn = g_ & 3;               // 0..3 (128-col tiles)

  const int lane = tid & 63;
  const int w = tid >> 6;
  const int wm = w >> 1, wn = w & 1;   // 2x2 wave grid over 128x128
  const int l15 = lane & 15, quad = lane >> 4;

  // staging: tid -> (row = tid>>2, 16B piece = tid&3)
  const int srow = tid >> 2;
  const int spc8 = (tid & 3) * 8;
  const f16* gA  = Xh + (size_t)(bm * 128 + srow) * K_ + spc8;
  const f16* gBg = Wp + (size_t)(bn * 128 + srow) * K_ + spc8;
  const f16* gBc = Wp + (size_t)(512 + bn * 128 + srow) * K_ + spc8;
  f16* lA  = sA  + tid * 8;
  f16* lBg = sBg + tid * 8;
  f16* lBc = sBc + tid * 8;

  f32x4 accG[4][4] = {};
  f32x4 accC[4][4] = {};

  for (int k0 = 0; k0 < K_; k0 += 32) {
    async16(gA + k0,  lA);
    async16(gA + (size_t)64 * K_ + k0,  lA  + 64 * 32);
    async16(gBg + k0, lBg);
    async16(gBg + (size_t)64 * K_ + k0, lBg + 64 * 32);
    async16(gBc + k0, lBc);
    async16(gBc + (size_t)64 * K_ + k0, lBc + 64 * 32);
    __syncthreads();  // drains vmcnt then barrier

    f16x8 af[4], bgf[4], bcf[4];
#pragma unroll
    for (int i = 0; i < 4; i++)
      af[i]  = *(const f16x8*)(sA  + (wm * 64 + i * 16 + l15) * 32 + quad * 8);
#pragma unroll
    for (int j = 0; j < 4; j++) {
      bgf[j] = *(const f16x8*)(sBg + (wn * 64 + j * 16 + l15) * 32 + quad * 8);
      bcf[j] = *(const f16x8*)(sBc + (wn * 64 + j * 16 + l15) * 32 + quad * 8);
    }
#pragma unroll
    for (int i = 0; i < 4; i++)
#pragma unroll
      for (int j = 0; j < 4; j++) {
        accG[i][j] = __builtin_amdgcn_mfma_f32_16x16x32_f16(af[i], bgf[j], accG[i][j], 0, 0, 0);
        accC[i][j] = __builtin_amdgcn_mfma_f32_16x16x32_f16(af[i], bcf[j], accC[i][j], 0, 0, 0);
      }
    __syncthreads();
  }

  // epilogue: add bias, pack (yg, yc) as f16x2 -> one 4B store per cell
#pragma unroll
  for (int j = 0; j < 4; j++) {
    const int col = bn * 128 + wn * 64 + j * 16 + l15;   // 0..511
    const float bgv = bg[col];
    const float bcv = bc[col];
#pragma unroll
    for (int i = 0; i < 4; i++) {
      const int mrow = bm * 128 + wm * 64 + i * 16 + quad * 4;
#pragma unroll
      for (int r = 0; r < 4; r++) {
        float yg = accG[i][j][r] + bgv;
        float yc = accC[i][j][r] + bcv;
        AC[(size_t)(mrow + r) * 512 + col] = pack2(yg, yc);
      }
    }
  }
}

// ---------------- single-pass scan with decoupled lookback ----------------
// 512 blocks x 512 threads. Virtual block id via atomic counter (blocks that
// start first get lower ids -> a block only waits on already-started blocks
// -> deadlock-free regardless of dispatch order).
// Thread d of chunk v: loads preacts (yg,yc), computes a=1-sig(yg),
// b=sig(yg)*tanh(yc), keeps packed in regs, composite (P,Q) published as
// packed f16x2 (flag 1 = aggregate, 2 = inclusive-from-seq-start).
// Lookback folds predecessors until an inclusive entry, then applies.
__global__ __launch_bounds__(512, 4) void scan_lb(
    const uint32_t* __restrict__ AC,
    uint32_t* __restrict__ agg, uint32_t* __restrict__ inc,
    volatile uint32_t* __restrict__ flags, uint32_t* __restrict__ counter,
    float* __restrict__ out) {
  __shared__ uint32_t s_vbid;
  __shared__ uint32_t s_flag;
  const int tid = threadIdx.x;
  if (tid == 0) s_vbid = atomicAdd(counter, 1u) & (NCHUNK - 1);
  __syncthreads();
  const int v = (int)s_vbid;           // 0..511
  const int ch = v & (NC_SEQ - 1);     // chunk index within sequence
  const size_t base = (size_t)v * CHUNK * 512 + tid;

  // ---- phase A: activations + local composite, ab register-resident ----
  uint32_t ab[CHUNK];
  float P = 1.0f, Q = 0.0f;
#pragma unroll
  for (int t = 0; t < CHUNK; t++) {
    f16x2 pv = __builtin_bit_cast(f16x2, AC[base + (size_t)t * 512]);
    float yg = (float)pv[0];
    float yc = (float)pv[1];
    float a = 1.0f / (1.0f + __expf(yg));          // 1 - sigmoid(yg)
    float e = __expf(fmaxf(-2.0f * yc, -30.0f));   // tanh via exp(-2x)
    float c = (1.0f - e) / (1.0f + e);             // tanh(yc)
    float b = (1.0f - a) * c;
    ab[t] = pack2(a, b);
    Q = fmaf(a, Q, b);
    P *= a;
  }

  // ---- publish ----
  uint32_t pq = pack2(P, Q);
  float hpre;
  if (ch == 0) {
    __hip_atomic_store(&inc[v * 512 + tid], pq, __ATOMIC_RELAXED,
                       __HIP_MEMORY_SCOPE_AGENT);
    __threadfence();
    __syncthreads();
    if (tid == 0)
      __hip_atomic_store((uint32_t*)&flags[v], 2u, __ATOMIC_RELEASE,
                         __HIP_MEMORY_SCOPE_AGENT);
    hpre = 0.0f;
  } else {
    __hip_atomic_store(&agg[v * 512 + tid], pq, __ATOMIC_RELAXED,
                       __HIP_MEMORY_SCOPE_AGENT);
    __threadfence();
    __syncthreads();
    if (tid == 0)
      __hip_atomic_store((uint32_t*)&flags[v], 1u, __ATOMIC_RELEASE,
                         __HIP_MEMORY_SCOPE_AGENT);

    // ---- lookback: fold aggregates until an inclusive entry ----
    float Pr = 1.0f, Qr = 0.0f;        // composite of chunks (j+1 .. v-1)
    int j = v - 1;
    for (;;) {
      if (tid == 0) {
        uint32_t f;
        do {
          f = __hip_atomic_load((uint32_t*)&flags[j], __ATOMIC_ACQUIRE,
                                __HIP_MEMORY_SCOPE_AGENT);
          if (f == 0) __builtin_amdgcn_s_sleep(8);
        } while (f == 0);
        s_flag = f;
      }
      __syncthreads();
      const uint32_t f = s_flag;
      const uint32_t* src = (f == 2) ? &inc[j * 512 + tid] : &agg[j * 512 + tid];
      uint32_t pj = __hip_atomic_load(src, __ATOMIC_RELAXED,
                                      __HIP_MEMORY_SCOPE_AGENT);
      f16x2 vj = __builtin_bit_cast(f16x2, pj);
      float Pj = (float)vj[0], Qj = (float)vj[1];
      float Pr_old = Pr;
      Pr = Pr * Pj;                    // prepend chunk j's composite
      Qr = fmaf(Pr_old, Qj, Qr);
      __syncthreads();                 // protect s_flag reuse
      if (f == 2) break;
      j--;
    }
    // publish inclusive: T_inc = T_own o T_ex
    float Pinc = P * Pr;
    float Qinc = fmaf(P, Qr, Q);
    __hip_atomic_store(&inc[v * 512 + tid], pack2(Pinc, Qinc),
                       __ATOMIC_RELAXED, __HIP_MEMORY_SCOPE_AGENT);
    __threadfence();
    __syncthreads();
    if (tid == 0)
      __hip_atomic_store((uint32_t*)&flags[v], 2u, __ATOMIC_RELEASE,
                         __HIP_MEMORY_SCOPE_AGENT);
    hpre = Qr;                         // exclusive prefix applied to h0 = 0
  }

  // ---- phase B: apply from registers ----
  float h = hpre;
#pragma unroll
  for (int t = 0; t < CHUNK; t++) {
    f16x2 vv = __builtin_bit_cast(f16x2, ab[t]);
    h = fmaf((float)vv[0], h, (float)vv[1]);
    out[base + (size_t)t * 512] = h;
  }
}

// ---------------- launch ----------------
extern "C" void kernel_launch(void* const* d_in, const int* in_sizes, int n_in,
                              void* d_out, int out_size, void* d_ws, size_t ws_size,
                              hipStream_t stream) {
  const float* x  = (const float*)d_in[0];
  const float* Wg = (const float*)d_in[1];
  const float* bg = (const float*)d_in[2];
  const float* Wc = (const float*)d_in[3];
  const float* bc = (const float*)d_in[4];
  float* out = (float*)d_out;

  char* ws = (char*)d_ws;
  // workspace layout (bytes), total ~99.0 MiB (proven budget >= 100 MiB):
  //   [0, 32MiB)             xh    f16 x
  //   [32MiB, 33MiB)         wp    f16 packed weights [1024][512]
  //   [33MiB, 97MiB)         AC    u32 packed (yg,yc) f16x2 [32768][512]
  //   [97MiB, 98MiB)         agg   u32 packed (P,Q) f16x2 per chunk x d
  //   [98MiB, 99MiB)         inc   u32 packed inclusive (P,Q)
  //   [99MiB, +2KiB)         flags u32[512]
  //   then                   counter u32
  f16*      xh    = (f16*)(ws);
  f16*      wp    = (f16*)(ws + 33554432);
  uint32_t* AC    = (uint32_t*)(ws + 34603008);
  uint32_t* agg   = (uint32_t*)(ws + 101711872);
  uint32_t* inc   = (uint32_t*)(ws + 102760448);
  uint32_t* flags = (uint32_t*)(ws + 103809024);
  uint32_t* cnt   = (uint32_t*)(ws + 103811072);

  prep<<<16897, 256, 0, stream>>>(x, Wg, Wc, xh, wp, flags, cnt);
  gemm_act<<<(M_ / 128) * 4, 256, 0, stream>>>(xh, wp, bg, bc, AC);

  scan_lb<<<NCHUNK, 512, 0, stream>>>(AC, agg, inc, flags, cnt, out);
}

// Round 7
// 496.588 us; speedup vs baseline: 1.6520x; 1.6520x over previous
//
#include <hip/hip_runtime.h>
#include <stdint.h>
#include <stddef.h>

// Problem constants
#define B_ 4
#define L_ 8192
#define D_ 512
#define M_ (B_*L_)      // 32768 rows
#define K_ 512
#define CHUNK 64
#define NC_SEQ (L_/CHUNK)    // 128 chunks per sequence

typedef _Float16 f16;
typedef f16 f16x2 __attribute__((ext_vector_type(2)));
typedef f16 f16x4 __attribute__((ext_vector_type(4)));
typedef f16 f16x8 __attribute__((ext_vector_type(8)));
typedef __fp16 h16x2 __attribute__((ext_vector_type(2)));   // cvt_pkrtz result type
typedef float f32x4 __attribute__((ext_vector_type(4)));

__device__ __forceinline__ uint32_t pack2(float a, float b) {
  h16x2 p = __builtin_amdgcn_cvt_pkrtz(a, b);
  return __builtin_bit_cast(uint32_t, p);
}

// activation pair from packed preacts: a = 1-sigmoid(yg), b = sigmoid(yg)*tanh(yc)
__device__ __forceinline__ void act_ab(uint32_t raw, float& a, float& b) {
  f16x2 v = __builtin_bit_cast(f16x2, raw);
  float yg = (float)v[0];
  float yc = (float)v[1];
  a = 1.0f / (1.0f + __expf(yg));            // 1 - sigmoid(yg)
  float e = __expf(fmaxf(-2.0f * yc, -30.0f));
  float c = (1.0f - e) / (1.0f + e);         // tanh(yc)
  b = (1.0f - a) * c;
}

// ---------------- async global->LDS (16B/lane) ----------------
__device__ __forceinline__ void async16(const void* g, void* l) {
  __builtin_amdgcn_global_load_lds(
      (const __attribute__((address_space(1))) uint32_t*)g,
      (__attribute__((address_space(3))) uint32_t*)l,
      16, 0, 0);
}

// ---------------- prep: cvt x -> f16, pack W -> f16 ----------------
// blocks [0, 16384)     : x fp32 -> f16
// blocks [16384, 16896) : Wg++Wc fp32 -> f16 packed [1024][512]
__global__ __launch_bounds__(256) void prep(
    const float* __restrict__ x, const float* __restrict__ Wg,
    const float* __restrict__ Wc, f16* __restrict__ xh,
    f16* __restrict__ wp) {
  const int blk = blockIdx.x;
  const int tid = threadIdx.x;
  if (blk < 16384) {
    int idx = (blk * 256 + tid) * 4;
    float4 v = *(const float4*)(x + idx);
    f16x4 o = {(f16)v.x, (f16)v.y, (f16)v.z, (f16)v.w};
    *(f16x4*)(xh + idx) = o;
  } else {
    int idx = ((blk - 16384) * 256 + tid) * 4;   // 0..524287
    const float* src = (idx < 262144) ? (Wg + idx) : (Wc + (idx - 262144));
    float4 v = *(const float4*)src;
    f16x4 o = {(f16)v.x, (f16)v.y, (f16)v.z, (f16)v.w};
    *(f16x4*)(wp + idx) = o;
  }
}

// ---------------- fused dual-B GEMM, packed f16x2 pre-activation out -----
// yg = Xh·Wg^T + bg ; yc = Xh·Wc^T + bc
// AC[m*512 + col] = pack_f16x2(yg, yc)
__global__ __launch_bounds__(256, 4) void gemm_act(
    const f16* __restrict__ Xh, const f16* __restrict__ Wp,
    const float* __restrict__ bg, const float* __restrict__ bc,
    uint32_t* __restrict__ AC) {
  __shared__ __align__(16) f16 sA[128 * 32];
  __shared__ __align__(16) f16 sBg[128 * 32];
  __shared__ __align__(16) f16 sBc[128 * 32];

  const int tid = threadIdx.x;
  // XCD swizzle: same bm-tile's 4 col-blocks run consecutively on one XCD
  const int id = blockIdx.x;           // 0..1023
  const int xcd = id & 7;
  const int slot = id >> 3;            // 0..127
  const int g_ = xcd * 128 + slot;
  const int bm = g_ >> 2;              // 0..255
  const int bn = g_ & 3;               // 0..3 (128-col tiles)

  const int lane = tid & 63;
  const int w = tid >> 6;
  const int wm = w >> 1, wn = w & 1;   // 2x2 wave grid over 128x128
  const int l15 = lane & 15, quad = lane >> 4;

  // staging: tid -> (row = tid>>2, 16B piece = tid&3)
  const int srow = tid >> 2;
  const int spc8 = (tid & 3) * 8;
  const f16* gA  = Xh + (size_t)(bm * 128 + srow) * K_ + spc8;
  const f16* gBg = Wp + (size_t)(bn * 128 + srow) * K_ + spc8;
  const f16* gBc = Wp + (size_t)(512 + bn * 128 + srow) * K_ + spc8;
  f16* lA  = sA  + tid * 8;
  f16* lBg = sBg + tid * 8;
  f16* lBc = sBc + tid * 8;

  f32x4 accG[4][4] = {};
  f32x4 accC[4][4] = {};

  for (int k0 = 0; k0 < K_; k0 += 32) {
    async16(gA + k0,  lA);
    async16(gA + (size_t)64 * K_ + k0,  lA  + 64 * 32);
    async16(gBg + k0, lBg);
    async16(gBg + (size_t)64 * K_ + k0, lBg + 64 * 32);
    async16(gBc + k0, lBc);
    async16(gBc + (size_t)64 * K_ + k0, lBc + 64 * 32);
    __syncthreads();  // drains vmcnt then barrier

    f16x8 af[4], bgf[4], bcf[4];
#pragma unroll
    for (int i = 0; i < 4; i++)
      af[i]  = *(const f16x8*)(sA  + (wm * 64 + i * 16 + l15) * 32 + quad * 8);
#pragma unroll
    for (int j = 0; j < 4; j++) {
      bgf[j] = *(const f16x8*)(sBg + (wn * 64 + j * 16 + l15) * 32 + quad * 8);
      bcf[j] = *(const f16x8*)(sBc + (wn * 64 + j * 16 + l15) * 32 + quad * 8);
    }
#pragma unroll
    for (int i = 0; i < 4; i++)
#pragma unroll
      for (int j = 0; j < 4; j++) {
        accG[i][j] = __builtin_amdgcn_mfma_f32_16x16x32_f16(af[i], bgf[j], accG[i][j], 0, 0, 0);
        accC[i][j] = __builtin_amdgcn_mfma_f32_16x16x32_f16(af[i], bcf[j], accC[i][j], 0, 0, 0);
      }
    __syncthreads();
  }

  // epilogue: add bias, pack (yg, yc) as f16x2 -> one 4B store per cell
#pragma unroll
  for (int j = 0; j < 4; j++) {
    const int col = bn * 128 + wn * 64 + j * 16 + l15;   // 0..511
    const float bgv = bg[col];
    const float bcv = bc[col];
#pragma unroll
    for (int i = 0; i < 4; i++) {
      const int mrow = bm * 128 + wm * 64 + i * 16 + quad * 4;
#pragma unroll
      for (int r = 0; r < 4; r++) {
        float yg = accG[i][j][r] + bgv;
        float yc = accC[i][j][r] + bcv;
        AC[(size_t)(mrow + r) * 512 + col] = pack2(yg, yc);
      }
    }
  }
}

// ---------------- scan pass 1: per-chunk composite only ----------------
// h_t = a_t h_{t-1} + b_t ; chunk composite: h_out = P*h_in + Q
__global__ __launch_bounds__(512) void scan_local(
    const uint32_t* __restrict__ AC,
    float* __restrict__ cA, float* __restrict__ cB) {
  const int blk = blockIdx.x;          // 0..511 = b*NC_SEQ + ch
  const int d = threadIdx.x;
  const size_t base = (size_t)blk * CHUNK * 512 + d;
  float P = 1.0f, Q = 0.0f;
#pragma unroll 4
  for (int t = 0; t < CHUNK; t++) {
    float a, b;
    act_ab(AC[base + (size_t)t * 512], a, b);
    Q = fmaf(a, Q, b);
    P *= a;
  }
  cA[blk * 512 + d] = P;
  cB[blk * 512 + d] = Q;
}

// ---------------- scan pass 2: wave-parallel prefix over chunks ----------
// One wave per (b, d): lane i serially combines chunks 2i,2i+1, then
// Kogge-Stone inclusive scan over 64 lanes via shfl_up, shift to exclusive,
// write Hp (h entering each chunk, h0 = 0).
__global__ __launch_bounds__(256) void scan_mid(
    const float* __restrict__ cA, const float* __restrict__ cB,
    float* __restrict__ Hp) {
  const int wid = blockIdx.x * 4 + (threadIdx.x >> 6);  // 0..2047
  const int lane = threadIdx.x & 63;
  const int b = wid >> 9;            // 0..3
  const int d = wid & 511;
  const int ch0 = lane * 2;
  const int i0 = (b * NC_SEQ + ch0) * 512 + d;
  const float Pa = cA[i0],        Qa = cB[i0];
  const float Pb = cA[i0 + 512],  Qb = cB[i0 + 512];
  // lane-local: combine(T[ch0], T[ch0+1])
  float P = Pa * Pb;
  float Q = fmaf(Pb, Qa, Qb);
  // inclusive Kogge-Stone over lanes: cur = combine(prev_window, cur_window)
#pragma unroll
  for (int off = 1; off < 64; off <<= 1) {
    float Pp = __shfl_up(P, off, 64);
    float Qp = __shfl_up(Q, off, 64);
    if (lane >= off) {
      Q = fmaf(P, Qp, Q);            // Q = P_cur*Q_prev + Q_cur
      P = P * Pp;
    }
  }
  // exclusive = inclusive shifted by one lane
  float Qe = __shfl_up(Q, 1, 64);
  if (lane == 0) Qe = 0.0f;          // h0 = 0
  // h entering chunk ch0 ; h entering chunk ch0+1
  Hp[i0] = Qe;
  Hp[i0 + 512] = fmaf(Pa, Qe, Qa);
}

// ---------------- scan pass 3: recompute activations, apply, write h -----
__global__ __launch_bounds__(512) void scan_apply(
    const uint32_t* __restrict__ AC, const float* __restrict__ Hp,
    float* __restrict__ out) {
  const int blk = blockIdx.x;
  const int d = threadIdx.x;
  const size_t base = (size_t)blk * CHUNK * 512 + d;
  float h = Hp[blk * 512 + d];
#pragma unroll 4
  for (int t = 0; t < CHUNK; t++) {
    const size_t i = base + (size_t)t * 512;
    float a, b;
    act_ab(AC[i], a, b);
    h = fmaf(a, h, b);
    out[i] = h;
  }
}

// ---------------- launch ----------------
extern "C" void kernel_launch(void* const* d_in, const int* in_sizes, int n_in,
                              void* d_out, int out_size, void* d_ws, size_t ws_size,
                              hipStream_t stream) {
  const float* x  = (const float*)d_in[0];
  const float* Wg = (const float*)d_in[1];
  const float* bg = (const float*)d_in[2];
  const float* Wc = (const float*)d_in[3];
  const float* bc = (const float*)d_in[4];
  float* out = (float*)d_out;

  char* ws = (char*)d_ws;
  // workspace layout (bytes), ~100 MiB (proven budget):
  //   [0, 32MiB)       xh   f16 x
  //   [32MiB, 33MiB)   wp   f16 packed weights [1024][512]
  //   [33MiB, 97MiB)   AC   u32 packed (yg,yc) f16x2 [32768][512]
  //   [97MiB..]        cA, cB, Hp fp32 (1MiB each)
  f16*      xh = (f16*)(ws);
  f16*      wp = (f16*)(ws + 33554432);
  uint32_t* AC = (uint32_t*)(ws + 34603008);
  float*    cA = (float*)(ws + 101711872);
  float*    cB = (float*)(ws + 102760448);
  float*    Hp = (float*)(ws + 103809024);

  prep<<<16896, 256, 0, stream>>>(x, Wg, Wc, xh, wp);
  gemm_act<<<(M_ / 128) * 4, 256, 0, stream>>>(xh, wp, bg, bc, AC);
  scan_local<<<B_ * NC_SEQ, 512, 0, stream>>>(AC, cA, cB);
  scan_mid<<<512, 256, 0, stream>>>(cA, cB, Hp);
  scan_apply<<<B_ * NC_SEQ, 512, 0, stream>>>(AC, Hp, out);
}